// Round 13
// baseline (266.361 us; speedup 1.0000x reference)
//
#include <hip/hip_runtime.h>
#include <math.h>

// STC loss forward on MI355X — Round 25: R24's fused emit+scan ready-flag
// overlap + s_setprio role split (T5 in its documented regime).
//
// R24 post-mortem: absmax 0 (flag machinery sound) but fused dur 211us —
// each scan block's CU hosts ~15 emit blocks (~30 waves); round-robin issue
// arbitration inflated the latency-bound serial chain 139 -> ~420 cy/step.
// Emit must run ONLY in the chain's stall cycles. Fix: scan waves
// s_setprio(3) (win every arbitration), emit waves s_setprio(0). One
// instruction per branch; flag-spin already s_sleeps.
//
// Everything else R24-verbatim (which was R23-verbatim scan + flag waits):
//   grid = 32 scan blocks (dispatched first) + 4000 emit blocks (16-row
//   pair each, low/high interleaved). Emit: write -> __syncthreads ->
//   __threadfence -> atomicExch(flag). Scan: grouped 16-pair flag wait
//   every 16 chunks; counted-vmcnt pipeline; bidirectional fwd/bwd waves
//   meeting at t*=1007/1008; LSE combine * ln2; atomicAdd(out).
// Pre-commit: if total >= 133us, overlap is closed — revert R23, declare
// ceiling (scan serial floor 58.5us + emit 13us + harness 64.7us).

#define T_LEN   2000
#define BATCH   32
#define NCLS    128
#define LTGT    100
#define NEG_INF_F (-1e30f)

typedef float f32x4 __attribute__((ext_vector_type(4)));

#if __has_builtin(__builtin_amdgcn_exp2f)
#define EXP2(x) __builtin_amdgcn_exp2f(x)
#else
#define EXP2(x) exp2f(x)
#endif
#if __has_builtin(__builtin_amdgcn_logf)
#define LOG2(x) __builtin_amdgcn_logf(x)
#else
#define LOG2(x) __log2f(x)
#endif

// DPP wave shifts, lane-boundary value = NEG_INF via old + bound_ctrl=false.
__device__ __forceinline__ float shift_up1_ninf(float x)  // lane i <- i-1
{
    return __int_as_float(
        __builtin_amdgcn_update_dpp(__float_as_int(NEG_INF_F),
                                    __float_as_int(x), 0x138, 0xf, 0xf, false));
}
__device__ __forceinline__ float shift_dn1_ninf(float x)  // lane i <- i+1
{
    return __int_as_float(
        __builtin_amdgcn_update_dpp(__float_as_int(NEG_INF_F),
                                    __float_as_int(x), 0x130, 0xf, 0xf, false));
}

// pinned-issue async load (bare ext_vector output) + counted manual waits
#define GL4(dst, base, imm)                                             \
    asm volatile("global_load_dwordx4 %0, %1, off offset:" #imm         \
                 : "=&v"(dst) : "v"(base))
#define VMWAIT(n) do {                                                  \
        asm volatile("s_waitcnt vmcnt(" #n ")" ::: "memory");           \
        __builtin_amdgcn_sched_barrier(0);                              \
    } while (0)

__global__ void __launch_bounds__(128, 1)
stc_fused(const float* __restrict__ inputs,   // (T,B,C) log-softmax (natural)
          const int*   __restrict__ targets,  // (B,L)
          float4*      __restrict__ tabA,
          float*       __restrict__ tabB,
          unsigned*    __restrict__ flags,    // [BATCH][128], pair p ready==1
          float*       __restrict__ out,
          const float wt)
{
    const int lane = threadIdx.x & 63;
    const int wave = threadIdx.x >> 6;

    __shared__ float lps[2][8][NCLS];        // emit staging (per-wave half)
    __shared__ float sb[4][64];              // scan beta handoff

    if (blockIdx.x >= BATCH) {
        // ================= emission producer (prio 0) =================
        __builtin_amdgcn_s_setprio(0);       // yield issue slots to scan
        const int e  = blockIdx.x - BATCH;   // 0..3999
        const int b  = e & 31;
        const int m  = e >> 5;               // 0..124
        // interleave low/high pairs so both scan directions start early
        const int pair  = (m & 1) ? (124 - (m >> 1)) : (m >> 1);
        const int tbase = pair * 16 + wave * 8;

        int tg0 = 0, tg1 = 0;
        if (lane < 50) {
            tg0 = targets[b * LTGT + 2 * lane];
            tg1 = targets[b * LTGT + 2 * lane + 1];
        }
        const float L2E = 1.4426950408889634f;

#define ELD(i) const float2 x##i = *(const float2*)(inputs +                 \
                   ((size_t)(tbase + (i)) * BATCH + b) * NCLS + 2 * lane);
        ELD(0) ELD(1) ELD(2) ELD(3) ELD(4) ELD(5) ELD(6) ELD(7)
#undef ELD
#define EST(i) *(float2*)&lps[wave][i][2 * lane] = x##i;
        EST(0) EST(1) EST(2) EST(3) EST(4) EST(5) EST(6) EST(7)
#undef EST
#define EPART(i) const float ex##i = __expf(x##i.x);                          \
                 float p##i = (lane == 0) ? __expf(x##i.y)                    \
                                          : ex##i + __expf(x##i.y);
        EPART(0) EPART(1) EPART(2) EPART(3) EPART(4) EPART(5) EPART(6) EPART(7)
#undef EPART
#define ERED(off) p0 += __shfl_xor(p0, off, 64); p1 += __shfl_xor(p1, off, 64);\
                  p2 += __shfl_xor(p2, off, 64); p3 += __shfl_xor(p3, off, 64);\
                  p4 += __shfl_xor(p4, off, 64); p5 += __shfl_xor(p5, off, 64);\
                  p6 += __shfl_xor(p6, off, 64); p7 += __shfl_xor(p7, off, 64);
        ERED(32) ERED(16) ERED(8) ERED(4) ERED(2) ERED(1)
#undef ERED
#define EPB(i) const float pb##i = __shfl(ex##i, 0, 64);
        EPB(0) EPB(1) EPB(2) EPB(3) EPB(4) EPB(5) EPB(6) EPB(7)
#undef EPB
        if (lane < 50) {
#define EOUT(i) do {                                                          \
        const float lt0 = lps[wave][i][tg0], lt1 = lps[wave][i][tg1];         \
        const float aa  = fmaf(wt * (1.0f + 1e-7f), p##i, pb##i);             \
        const float q0  = fmaf(-wt, __expf(lt0), aa);                         \
        const float q1  = fmaf(-wt, __expf(lt1), aa);                         \
        tabA[((size_t)b * T_LEN + tbase + (i)) * 50 + lane] =                 \
            make_float4(L2E * lt0, L2E * lt1, LOG2(q0), LOG2(q1));            \
    } while (0);
            EOUT(0) EOUT(1) EOUT(2) EOUT(3) EOUT(4) EOUT(5) EOUT(6) EOUT(7)
#undef EOUT
        } else if (lane == 50) {
#define EOB(i) tabB[(size_t)b * T_LEN + tbase + (i)] =                        \
                   LOG2(fmaf(wt, p##i, pb##i));
            EOB(0) EOB(1) EOB(2) EOB(3) EOB(4) EOB(5) EOB(6) EOB(7)
#undef EOB
        }

        __syncthreads();                     // both waves' stores drained
        if (threadIdx.x == 0) {
            __threadfence();                 // device-scope release
            atomicExch(&flags[b * 128 + pair], 1u);
        }
        return;
    }

    // ================= scan (prio 3 — wins every issue arbitration) ======
    __builtin_amdgcn_s_setprio(3);
    const int b    = blockIdx.x;
    const int fb   = b * 128;
    const bool l50 = (lane == 50);

    const int tb0 = b * LTGT;
    const int c0 = 2 * lane, c1 = 2 * lane + 1;
    bool skb0 = false, skb1 = false;
    if (c0 >= 1 && c0 <= 99)
        skb0 = (targets[tb0 + c0] != targets[tb0 + c0 - 1]);
    if (c1 <= 99)
        skb1 = (targets[tb0 + c1] != targets[tb0 + c1 - 1]);

    const char* gAc = (const char*)tabA + (size_t)b * T_LEN * 800
                    + (size_t)lane * 16;
    const char* gQc = (const char*)(tabB + (size_t)b * T_LEN);

    // drain compiler-issued loads so manual vmcnt counts are exact
    asm volatile("s_waitcnt vmcnt(0) lgkmcnt(0)" ::: "memory");
    __builtin_amdgcn_sched_barrier(0);

    // grouped ready-wait: pairs [g0, g0+np) (fwd) / [ph-np+1, ph] (bwd).
#define FWAITF(g0) do {                                                 \
        const int np_ = (63 - (g0)) < 16 ? (63 - (g0)) : 16;            \
        for (;;) {                                                      \
            unsigned v_ = 1u;                                           \
            if (lane < np_)                                             \
                v_ = atomicAdd(&flags[fb + (g0) + lane], 0u);           \
            if (__all(v_ != 0u)) break;                                 \
            __builtin_amdgcn_s_sleep(8);                                \
        }                                                               \
        __threadfence();                                                \
        __builtin_amdgcn_sched_barrier(0);                              \
    } while (0)
#define FWAITB(k0) do {                                                 \
        const int ph_ = 124 - (k0);                                     \
        const int np_ = (ph_ - 62) < 16 ? (ph_ - 62) : 16;              \
        for (;;) {                                                      \
            unsigned v_ = 1u;                                           \
            if (lane < np_)                                             \
                v_ = atomicAdd(&flags[fb + ph_ - lane], 0u);            \
            if (__all(v_ != 0u)) break;                                 \
            __builtin_amdgcn_s_sleep(8);                                \
        }                                                               \
        __threadfence();                                                \
        __builtin_amdgcn_sched_barrier(0);                              \
    } while (0)

    f32x4 Xv0, Xv1, Xv2, Xv3, Xv4, Xv5, Xv6, Xv7,
          Xv8, Xv9, Xv10, Xv11, Xv12, Xv13, Xv14, Xv15, Xq0, Xq1, Xq2, Xq3;
    f32x4 Yv0, Yv1, Yv2, Yv3, Yv4, Yv5, Yv6, Yv7,
          Yv8, Yv9, Yv10, Yv11, Yv12, Yv13, Yv14, Yv15, Yq0, Yq1, Yq2, Yq3;

#define LOADB(P, trow) do {                                             \
        const char* a0_ = gAc + (size_t)(trow) * 800;                   \
        const char* a1_ = a0_ + 4000;                                   \
        const char* a2_ = a0_ + 8000;                                   \
        GL4(P##v0,  a0_, 0);    GL4(P##v1,  a0_, 800);                  \
        GL4(P##v2,  a0_, 1600); GL4(P##v3,  a0_, 2400);                 \
        GL4(P##v4,  a0_, 3200);                                         \
        GL4(P##v5,  a1_, 0);    GL4(P##v6,  a1_, 800);                  \
        GL4(P##v7,  a1_, 1600); GL4(P##v8,  a1_, 2400);                 \
        GL4(P##v9,  a1_, 3200);                                         \
        GL4(P##v10, a2_, 0);    GL4(P##v11, a2_, 800);                  \
        GL4(P##v12, a2_, 1600); GL4(P##v13, a2_, 2400);                 \
        GL4(P##v14, a2_, 3200); GL4(P##v15, a2_, 4000);                 \
        const char* q_ = gQc + (size_t)(trow) * 4;                      \
        GL4(P##q0, q_, 0);  GL4(P##q1, q_, 16);                         \
        GL4(P##q2, q_, 32); GL4(P##q3, q_, 48);                         \
    } while (0)

    float A0 = (lane == 0) ? 0.0f : NEG_INF_F;
    float O0 = NEG_INF_F, A1 = NEG_INF_F, O1 = NEG_INF_F;
    float p0 = NEG_INF_F;

    if (wave == 0) {
        // ---------------- forward: 63 chunks, rows 0..1007 ----------------
#define FSTEP(vx, vy, vz, vw, qk) do {                                 \
        const float m1  = fmaxf(A1, O0);                               \
        const float lz1 = LOG2(1.0f + EXP2(-fabsf(A1 - O0)));          \
        const float ml1 = m1 + lz1;                                    \
        const float O1n = (skb1 ? ml1 : A1) + (vy);                    \
        const float psh = shift_up1_ninf(O1n);                         \
        A1 = ml1 + (vw);                                               \
        O1 = O1n;                                                      \
        const float m0  = fmaxf(A0, p0);                               \
        const float lz0 = LOG2(1.0f + EXP2(-fabsf(A0 - p0)));          \
        const float ml0 = m0 + lz0;                                    \
        const float lq0 = l50 ? (qk) : (vz);                           \
        O0 = (skb0 ? ml0 : A0) + (vx);                                 \
        A0 = ml0 + lq0;                                                \
        p0 = psh;                                                      \
    } while (0)
#define RUNF(P) do {                                                       \
        FSTEP(P##v0[0],  P##v0[1],  P##v0[2],  P##v0[3],  P##q0[0]);       \
        FSTEP(P##v1[0],  P##v1[1],  P##v1[2],  P##v1[3],  P##q0[1]);       \
        FSTEP(P##v2[0],  P##v2[1],  P##v2[2],  P##v2[3],  P##q0[2]);       \
        FSTEP(P##v3[0],  P##v3[1],  P##v3[2],  P##v3[3],  P##q0[3]);       \
        FSTEP(P##v4[0],  P##v4[1],  P##v4[2],  P##v4[3],  P##q1[0]);       \
        FSTEP(P##v5[0],  P##v5[1],  P##v5[2],  P##v5[3],  P##q1[1]);       \
        FSTEP(P##v6[0],  P##v6[1],  P##v6[2],  P##v6[3],  P##q1[2]);       \
        FSTEP(P##v7[0],  P##v7[1],  P##v7[2],  P##v7[3],  P##q1[3]);       \
        FSTEP(P##v8[0],  P##v8[1],  P##v8[2],  P##v8[3],  P##q2[0]);       \
        FSTEP(P##v9[0],  P##v9[1],  P##v9[2],  P##v9[3],  P##q2[1]);       \
        FSTEP(P##v10[0], P##v10[1], P##v10[2], P##v10[3], P##q2[2]);       \
        FSTEP(P##v11[0], P##v11[1], P##v11[2], P##v11[3], P##q2[3]);       \
        FSTEP(P##v12[0], P##v12[1], P##v12[2], P##v12[3], P##q3[0]);       \
        FSTEP(P##v13[0], P##v13[1], P##v13[2], P##v13[3], P##q3[1]);       \
        FSTEP(P##v14[0], P##v14[1], P##v14[2], P##v14[3], P##q3[2]);       \
        FSTEP(P##v15[0], P##v15[1], P##v15[2], P##v15[3], P##q3[3]);       \
    } while (0)
        FWAITF(0);
        LOADB(X, 0);
        for (int c = 0; c + 1 < 63; c += 2) {
            LOADB(Y, 16 * (c + 1)); VMWAIT(20); RUNF(X);
            if (((c + 2) & 15) == 0) FWAITF(c + 2);
            LOADB(X, 16 * (c + 2)); VMWAIT(20); RUNF(Y);
        }
        VMWAIT(0); RUNF(X);                  // chunk 62 (rows 992..1007)
#undef RUNF
#undef FSTEP
    } else {
        // ---------------- backward: 62 chunks, rows 1999..1008 ------------
        float bA0 = l50 ? 0.0f : NEG_INF_F;          // bA[100] = 0
        float bA1 = NEG_INF_F;
        float bO0 = NEG_INF_F;
        float bO1 = (lane == 49) ? 0.0f : NEG_INF_F; // bO[99] = 0
#define BSTEP(vx, vy, vz, vw, qk) do {                                 \
        const float x1  = bA1 + (vw);                                  \
        const float y1  = bO1 + (vy);                                  \
        const float m1  = fmaxf(x1, y1);                               \
        const float lz1 = LOG2(1.0f + EXP2(-fabsf(x1 - y1)));          \
        const float L1  = m1 + lz1;                                    \
        const float lq0 = l50 ? (qk) : (vz);                           \
        const float x0  = bA0 + lq0;                                   \
        const float y0  = bO0 + (vx);                                  \
        const float m0  = fmaxf(x0, y0);                               \
        const float lz0 = LOG2(1.0f + EXP2(-fabsf(x0 - y0)));          \
        const float L0  = m0 + lz0;                                    \
        const float t0  = skb0 ? L0 : x0;                              \
        const float psh = shift_dn1_ninf(t0);  /* lane i <- i+1 */     \
        bO0 = skb1 ? L1 : x1;                                          \
        bA0 = l50 ? x0 : L0;                                           \
        bA1 = L1;                                                      \
        bO1 = psh;                                                     \
    } while (0)
#define RUNBK(P) do {                                                      \
        BSTEP(P##v15[0], P##v15[1], P##v15[2], P##v15[3], P##q3[3]);       \
        BSTEP(P##v14[0], P##v14[1], P##v14[2], P##v14[3], P##q3[2]);       \
        BSTEP(P##v13[0], P##v13[1], P##v13[2], P##v13[3], P##q3[1]);       \
        BSTEP(P##v12[0], P##v12[1], P##v12[2], P##v12[3], P##q3[0]);       \
        BSTEP(P##v11[0], P##v11[1], P##v11[2], P##v11[3], P##q2[3]);       \
        BSTEP(P##v10[0], P##v10[1], P##v10[2], P##v10[3], P##q2[2]);       \
        BSTEP(P##v9[0],  P##v9[1],  P##v9[2],  P##v9[3],  P##q2[1]);       \
        BSTEP(P##v8[0],  P##v8[1],  P##v8[2],  P##v8[3],  P##q2[0]);       \
        BSTEP(P##v7[0],  P##v7[1],  P##v7[2],  P##v7[3],  P##q1[3]);       \
        BSTEP(P##v6[0],  P##v6[1],  P##v6[2],  P##v6[3],  P##q1[2]);       \
        BSTEP(P##v5[0],  P##v5[1],  P##v5[2],  P##v5[3],  P##q1[1]);       \
        BSTEP(P##v4[0],  P##v4[1],  P##v4[2],  P##v4[3],  P##q1[0]);       \
        BSTEP(P##v3[0],  P##v3[1],  P##v3[2],  P##v3[3],  P##q0[3]);       \
        BSTEP(P##v2[0],  P##v2[1],  P##v2[2],  P##v2[3],  P##q0[2]);       \
        BSTEP(P##v1[0],  P##v1[1],  P##v1[2],  P##v1[3],  P##q0[1]);       \
        BSTEP(P##v0[0],  P##v0[1],  P##v0[2],  P##v0[3],  P##q0[0]);       \
    } while (0)
        FWAITB(0);
        LOADB(X, 1984);
        for (int k = 0; k + 1 < 61; k += 2) {
            LOADB(Y, 1984 - 16 * (k + 1)); VMWAIT(20); RUNBK(X);
            if (((k + 2) & 15) == 0) FWAITB(k + 2);
            LOADB(X, 1984 - 16 * (k + 2)); VMWAIT(20); RUNBK(Y);
        }
        LOADB(Y, 1008); VMWAIT(20); RUNBK(X);  // chunk 60 (rows 1024..1039)
        VMWAIT(0); RUNBK(Y);                   // chunk 61 (rows 1008..1023)
#undef RUNBK
#undef BSTEP
        sb[0][lane] = bA0; sb[1][lane] = bA1;
        sb[2][lane] = bO0; sb[3][lane] = bO1;
    }
#undef LOADB
#undef FWAITF
#undef FWAITB

    __syncthreads();

    if (wave == 0) {
        // combine: LSE over all states of alpha_1007 + beta_1007
        const float bA0g = sb[0][lane], bA1g = sb[1][lane];
        const float bO0g = sb[2][lane], bO1g = sb[3][lane];
        const float T0 = (lane <= 50) ? A0 + bA0g : NEG_INF_F;
        const float T1 = (lane < 50)  ? A1 + bA1g : NEG_INF_F;
        const float T2 = (lane < 50)  ? O0 + bO0g : NEG_INF_F;
        const float T3 = (lane < 50)  ? O1 + bO1g : NEG_INF_F;
        float M = fmaxf(fmaxf(T0, T1), fmaxf(T2, T3));
        float S = EXP2(T0 - M) + EXP2(T1 - M) + EXP2(T2 - M) + EXP2(T3 - M);
        #pragma unroll
        for (int off = 32; off >= 1; off >>= 1) {
            const float Mo = __shfl_xor(M, off, 64);
            const float So = __shfl_xor(S, off, 64);
            const float Mn = fmaxf(M, Mo);
            S = S * EXP2(M - Mn) + So * EXP2(Mo - Mn);
            M = Mn;
        }
        if (lane == 0) {
            const float LN2 = 0.6931471805599453f;
            atomicAdd(out, -(M + LOG2(S)) * LN2
                               / ((float)T_LEN * (float)BATCH));
        }
    }
}

// ---------------------------------------------------------------- launch
extern "C" void kernel_launch(void* const* d_in, const int* in_sizes, int n_in,
                              void* d_out, int out_size, void* d_ws, size_t ws_size,
                              hipStream_t stream)
{
    const float* inputs  = (const float*)d_in[0];   // (2000,32,128) f32
    const int*   targets = (const int*)d_in[1];     // (32,100) i32
    float*       out     = (float*)d_out;           // scalar f32

    float4*   tabA  = (float4*)d_ws;                              // 51.2 MB
    float*    tabB  = (float*)((char*)d_ws + (size_t)51200000);   // 256 KB
    unsigned* flags = (unsigned*)((char*)d_ws + (size_t)51456000);// 16 KB

    // wt = WLAST + (W0-WLAST)*exp(-NSTEP*ln2/THALF)
    const float wt = (float)(0.1 + 0.9 * exp(-log(2.0) / 10000.0));

    (void)hipMemsetAsync(out, 0, sizeof(float), stream);
    (void)hipMemsetAsync(flags, 0, BATCH * 128 * sizeof(unsigned), stream);
    // grid: 32 scan blocks first (start immediately, spin on flags),
    // then 4000 emit blocks (one 16-row pair each).
    stc_fused<<<dim3(BATCH + BATCH * 125), dim3(128), 0, stream>>>(
        inputs, targets, tabA, tabB, flags, out, wt);
}

// Round 14
// 131.993 us; speedup vs baseline: 2.0180x; 2.0180x over previous
//
#include <hip/hip_runtime.h>
#include <math.h>

// STC loss forward on MI355X — Round 26: restore R23 (132.9us, absmax 0),
// the best passing kernel. This is the declared ceiling state.
//
// R25 post-mortem: s_setprio(3/0) role-split had ZERO effect on the fused
// overlap (204-225us ≈ R24's 211-225) — gfx950 wave priority does not
// starve co-resident waves enough to protect a latency-bound serial chain.
// Per pre-commit, the overlap family is closed. All structural families
// explored and closed: chain-shortening (R22: poly exp2 +51%), exp-domain
// (R19/R20: accuracy), coop fusion (R17: container kill), producer-consumer
// (R18: producer-bound), async overlap (R24/R25: issue arbitration).
//
// Ceiling arithmetic: scan = 1008 serial LSE steps x ~139cy (~66cy issue:
// 4 trans x 8cy + ~17 VALU x 2cy; rest trans->add join stalls) = 58.5us;
// emit = 84MB / 6.3TB/s = 13us; harness fixed = 64.7us (measured R18).
// Sum ~136us ~ measured 132.9us. More requires a shorter serial recurrence
// (2x bidirectional already taken; k-way segmentation prices at 101x basis
// work for 4x parallelism — net loss) or different hardware.
//
// Kernel structure (verified absmax 0 across R16/R21/R23):
//   emit: 8 rows/wave, level-major butterflies; zeroes *out via idle lane.
//   scan: 32 blocks x 2 waves (fwd rows 0..1007, bwd rows 1999..1008);
//   forced-register GL4 double-buffer + counted vmcnt; DPP lane shifts;
//   log2-domain LSE steps; combine LSE_s(alpha+beta) * ln2 at the meet.

#define T_LEN   2000
#define BATCH   32
#define NCLS    128
#define LTGT    100
#define CHUNK   16
#define EROWS   8
#define NEG_INF_F (-1e30f)

typedef float f32x4 __attribute__((ext_vector_type(4)));

#if __has_builtin(__builtin_amdgcn_exp2f)
#define EXP2(x) __builtin_amdgcn_exp2f(x)
#else
#define EXP2(x) exp2f(x)
#endif
#if __has_builtin(__builtin_amdgcn_logf)
#define LOG2(x) __builtin_amdgcn_logf(x)
#else
#define LOG2(x) __log2f(x)
#endif

// ---------------------------------------------------------------- K1: emissions
// tabA[(b*T+t)*50 + j] = (L2E*tok_2j, L2E*tok_2j+1, log2 q_2j, log2 q_2j+1)
// tabB[b*T+t] = log2(p_blank + wt*s)
__global__ void __launch_bounds__(64)
stc_emit(const float* __restrict__ inputs,   // (T,B,C) log-softmax (natural)
         const int*   __restrict__ targets,  // (B,L)
         float4*      __restrict__ tabA,
         float*       __restrict__ tabB,
         float*       __restrict__ out,
         const float wt)
{
    const int tbase = blockIdx.x * EROWS;
    const int b     = blockIdx.y;
    const int lane  = threadIdx.x;       // 1 wave per block, 8 rows per wave

    __shared__ float lps[EROWS][NCLS];

    // fold the output zeroing into this kernel (idle lane): one fewer
    // dispatch in the graph. emit completes before scan starts (stream order).
    if (blockIdx.x == 0 && blockIdx.y == 0 && lane == 51) *out = 0.0f;

    int tg0 = 0, tg1 = 0;
    if (lane < 50) {                     // same gather indices for all rows
        tg0 = targets[b * LTGT + 2 * lane];
        tg1 = targets[b * LTGT + 2 * lane + 1];
    }
    const float L2E = 1.4426950408889634f;

    // phase A: 8 independent global loads (one HBM latency for all)
#define ELD(i) const float2 x##i = *(const float2*)(inputs +                 \
                   ((size_t)(tbase + (i)) * BATCH + b) * NCLS + 2 * lane);
    ELD(0) ELD(1) ELD(2) ELD(3) ELD(4) ELD(5) ELD(6) ELD(7)
#undef ELD
    // phase A2: LDS writes (same-wave DS: in-order)
#define EST(i) *(float2*)&lps[i][2 * lane] = x##i;
    EST(0) EST(1) EST(2) EST(3) EST(4) EST(5) EST(6) EST(7)
#undef EST
    // phase B: per-lane partials
#define EPART(i) const float ex##i = __expf(x##i.x);                          \
                 float p##i = (lane == 0) ? __expf(x##i.y)                    \
                                          : ex##i + __expf(x##i.y);
    EPART(0) EPART(1) EPART(2) EPART(3) EPART(4) EPART(5) EPART(6) EPART(7)
#undef EPART
    // phase C: butterflies, LEVEL-major (8 independent shfls per level)
#define ERED(off) p0 += __shfl_xor(p0, off, 64); p1 += __shfl_xor(p1, off, 64);\
                  p2 += __shfl_xor(p2, off, 64); p3 += __shfl_xor(p3, off, 64);\
                  p4 += __shfl_xor(p4, off, 64); p5 += __shfl_xor(p5, off, 64);\
                  p6 += __shfl_xor(p6, off, 64); p7 += __shfl_xor(p7, off, 64);
    ERED(32) ERED(16) ERED(8) ERED(4) ERED(2) ERED(1)
#undef ERED
#define EPB(i) const float pb##i = __shfl(ex##i, 0, 64);
    EPB(0) EPB(1) EPB(2) EPB(3) EPB(4) EPB(5) EPB(6) EPB(7)
#undef EPB

    if (lane < 50) {
#define EOUT(i) do {                                                          \
        const float lt0 = lps[i][tg0], lt1 = lps[i][tg1];                     \
        const float aa  = fmaf(wt * (1.0f + 1e-7f), p##i, pb##i);             \
        const float q0  = fmaf(-wt, __expf(lt0), aa);                         \
        const float q1  = fmaf(-wt, __expf(lt1), aa);                         \
        tabA[((size_t)b * T_LEN + tbase + (i)) * 50 + lane] =                 \
            make_float4(L2E * lt0, L2E * lt1, LOG2(q0), LOG2(q1));            \
    } while (0);
        EOUT(0) EOUT(1) EOUT(2) EOUT(3) EOUT(4) EOUT(5) EOUT(6) EOUT(7)
#undef EOUT
    } else if (lane == 50) {
#define EOB(i) tabB[(size_t)b * T_LEN + tbase + (i)] =                        \
                   LOG2(fmaf(wt, p##i, pb##i));
        EOB(0) EOB(1) EOB(2) EOB(3) EOB(4) EOB(5) EOB(6) EOB(7)
#undef EOB
    }
}

// DPP wave shifts, lane-boundary value = NEG_INF via old + bound_ctrl=false.
__device__ __forceinline__ float shift_up1_ninf(float x)  // lane i <- i-1
{
    return __int_as_float(
        __builtin_amdgcn_update_dpp(__float_as_int(NEG_INF_F),
                                    __float_as_int(x), 0x138, 0xf, 0xf, false));
}
__device__ __forceinline__ float shift_dn1_ninf(float x)  // lane i <- i+1
{
    return __int_as_float(
        __builtin_amdgcn_update_dpp(__float_as_int(NEG_INF_F),
                                    __float_as_int(x), 0x130, 0xf, 0xf, false));
}

// pinned-issue async load (bare ext_vector output) + counted manual waits
#define GL4(dst, base, imm)                                             \
    asm volatile("global_load_dwordx4 %0, %1, off offset:" #imm         \
                 : "=&v"(dst) : "v"(base))
#define VMWAIT(n) do {                                                  \
        asm volatile("s_waitcnt vmcnt(" #n ")" ::: "memory");           \
        __builtin_amdgcn_sched_barrier(0);                              \
    } while (0)

// ---------------------------------------------------------------- K2: scan
__global__ void __launch_bounds__(128, 1)
stc_scan(const float4* __restrict__ tabA,
         const float*  __restrict__ tabB,
         const int*    __restrict__ targets,
         float*        __restrict__ out)
{
    const int b    = blockIdx.x;
    const int lane = threadIdx.x & 63;       // lane j owns cols 2j, 2j+1
    const int wave = threadIdx.x >> 6;       // 0 = forward, 1 = backward
    const bool l50 = (lane == 50);

    __shared__ float sb[4][64];              // beta handoff

    // skip gates (same masks serve fwd O'-gate and bwd t-gate)
    const int tb0 = b * LTGT;
    const int c0 = 2 * lane, c1 = 2 * lane + 1;
    bool skb0 = false, skb1 = false;
    if (c0 >= 1 && c0 <= 99)
        skb0 = (targets[tb0 + c0] != targets[tb0 + c0 - 1]);
    if (c1 <= 99)
        skb1 = (targets[tb0 + c1] != targets[tb0 + c1 - 1]);

    const char* gAc = (const char*)tabA + (size_t)b * T_LEN * 800
                    + (size_t)lane * 16;
    const char* gQc = (const char*)(tabB + (size_t)b * T_LEN);

    // drain compiler-issued loads so manual vmcnt counts are exact
    asm volatile("s_waitcnt vmcnt(0) lgkmcnt(0)" ::: "memory");
    __builtin_amdgcn_sched_barrier(0);

    f32x4 Xv0, Xv1, Xv2, Xv3, Xv4, Xv5, Xv6, Xv7,
          Xv8, Xv9, Xv10, Xv11, Xv12, Xv13, Xv14, Xv15, Xq0, Xq1, Xq2, Xq3;
    f32x4 Yv0, Yv1, Yv2, Yv3, Yv4, Yv5, Yv6, Yv7,
          Yv8, Yv9, Yv10, Yv11, Yv12, Yv13, Yv14, Yv15, Yq0, Yq1, Yq2, Yq3;

    // 20 loads per chunk; trow = starting time-row of the chunk
#define LOADB(P, trow) do {                                             \
        const char* a0_ = gAc + (size_t)(trow) * 800;                   \
        const char* a1_ = a0_ + 4000;                                   \
        const char* a2_ = a0_ + 8000;                                   \
        GL4(P##v0,  a0_, 0);    GL4(P##v1,  a0_, 800);                  \
        GL4(P##v2,  a0_, 1600); GL4(P##v3,  a0_, 2400);                 \
        GL4(P##v4,  a0_, 3200);                                         \
        GL4(P##v5,  a1_, 0);    GL4(P##v6,  a1_, 800);                  \
        GL4(P##v7,  a1_, 1600); GL4(P##v8,  a1_, 2400);                 \
        GL4(P##v9,  a1_, 3200);                                         \
        GL4(P##v10, a2_, 0);    GL4(P##v11, a2_, 800);                  \
        GL4(P##v12, a2_, 1600); GL4(P##v13, a2_, 2400);                 \
        GL4(P##v14, a2_, 3200); GL4(P##v15, a2_, 4000);                 \
        const char* q_ = gQc + (size_t)(trow) * 4;                      \
        GL4(P##q0, q_, 0);  GL4(P##q1, q_, 16);                         \
        GL4(P##q2, q_, 32); GL4(P##q3, q_, 48);                         \
    } while (0)

    // forward alpha state (wave0) — declared here so combine can read them
    float A0 = (lane == 0) ? 0.0f : NEG_INF_F;
    float O0 = NEG_INF_F, A1 = NEG_INF_F, O1 = NEG_INF_F;
    float p0 = NEG_INF_F;

    if (wave == 0) {
        // ---------------- forward: 63 chunks, rows 0..1007 ----------------
        // shared ml = m+lz (R13's proven ordering)
#define FSTEP(vx, vy, vz, vw, qk) do {                                 \
        const float m1  = fmaxf(A1, O0);                               \
        const float lz1 = LOG2(1.0f + EXP2(-fabsf(A1 - O0)));          \
        const float ml1 = m1 + lz1;                                    \
        const float O1n = (skb1 ? ml1 : A1) + (vy);                    \
        const float psh = shift_up1_ninf(O1n);                         \
        A1 = ml1 + (vw);                                               \
        O1 = O1n;                                                      \
        const float m0  = fmaxf(A0, p0);                               \
        const float lz0 = LOG2(1.0f + EXP2(-fabsf(A0 - p0)));          \
        const float ml0 = m0 + lz0;                                    \
        const float lq0 = l50 ? (qk) : (vz);                           \
        O0 = (skb0 ? ml0 : A0) + (vx);                                 \
        A0 = ml0 + lq0;                                                \
        p0 = psh;                                                      \
    } while (0)
#define RUNF(P) do {                                                       \
        FSTEP(P##v0[0],  P##v0[1],  P##v0[2],  P##v0[3],  P##q0[0]);       \
        FSTEP(P##v1[0],  P##v1[1],  P##v1[2],  P##v1[3],  P##q0[1]);       \
        FSTEP(P##v2[0],  P##v2[1],  P##v2[2],  P##v2[3],  P##q0[2]);       \
        FSTEP(P##v3[0],  P##v3[1],  P##v3[2],  P##v3[3],  P##q0[3]);       \
        FSTEP(P##v4[0],  P##v4[1],  P##v4[2],  P##v4[3],  P##q1[0]);       \
        FSTEP(P##v5[0],  P##v5[1],  P##v5[2],  P##v5[3],  P##q1[1]);       \
        FSTEP(P##v6[0],  P##v6[1],  P##v6[2],  P##v6[3],  P##q1[2]);       \
        FSTEP(P##v7[0],  P##v7[1],  P##v7[2],  P##v7[3],  P##q1[3]);       \
        FSTEP(P##v8[0],  P##v8[1],  P##v8[2],  P##v8[3],  P##q2[0]);       \
        FSTEP(P##v9[0],  P##v9[1],  P##v9[2],  P##v9[3],  P##q2[1]);       \
        FSTEP(P##v10[0], P##v10[1], P##v10[2], P##v10[3], P##q2[2]);       \
        FSTEP(P##v11[0], P##v11[1], P##v11[2], P##v11[3], P##q2[3]);       \
        FSTEP(P##v12[0], P##v12[1], P##v12[2], P##v12[3], P##q3[0]);       \
        FSTEP(P##v13[0], P##v13[1], P##v13[2], P##v13[3], P##q3[1]);       \
        FSTEP(P##v14[0], P##v14[1], P##v14[2], P##v14[3], P##q3[2]);       \
        FSTEP(P##v15[0], P##v15[1], P##v15[2], P##v15[3], P##q3[3]);       \
    } while (0)
        LOADB(X, 0);
        for (int c = 0; c + 1 < 63; c += 2) {
            LOADB(Y, 16 * (c + 1)); VMWAIT(20); RUNF(X);
            LOADB(X, 16 * (c + 2)); VMWAIT(20); RUNF(Y);
        }
        VMWAIT(0); RUNF(X);                  // chunk 62 (rows 992..1007)
#undef RUNF
#undef FSTEP
    } else {
        // ---------------- backward: 62 chunks, rows 1999..1008 ------------
        float bA0 = l50 ? 0.0f : NEG_INF_F;          // bA[100] = 0
        float bA1 = NEG_INF_F;
        float bO0 = NEG_INF_F;
        float bO1 = (lane == 49) ? 0.0f : NEG_INF_F; // bO[99] = 0
#define BSTEP(vx, vy, vz, vw, qk) do {                                 \
        const float x1  = bA1 + (vw);                                  \
        const float y1  = bO1 + (vy);                                  \
        const float m1  = fmaxf(x1, y1);                               \
        const float lz1 = LOG2(1.0f + EXP2(-fabsf(x1 - y1)));          \
        const float L1  = m1 + lz1;                                    \
        const float lq0 = l50 ? (qk) : (vz);                           \
        const float x0  = bA0 + lq0;                                   \
        const float y0  = bO0 + (vx);                                  \
        const float m0  = fmaxf(x0, y0);                               \
        const float lz0 = LOG2(1.0f + EXP2(-fabsf(x0 - y0)));          \
        const float L0  = m0 + lz0;                                    \
        const float t0  = skb0 ? L0 : x0;                              \
        const float psh = shift_dn1_ninf(t0);  /* lane i <- i+1 */     \
        bO0 = skb1 ? L1 : x1;                                          \
        bA0 = l50 ? x0 : L0;                                           \
        bA1 = L1;                                                      \
        bO1 = psh;                                                     \
    } while (0)
#define RUNBK(P) do {                                                      \
        BSTEP(P##v15[0], P##v15[1], P##v15[2], P##v15[3], P##q3[3]);       \
        BSTEP(P##v14[0], P##v14[1], P##v14[2], P##v14[3], P##q3[2]);       \
        BSTEP(P##v13[0], P##v13[1], P##v13[2], P##v13[3], P##q3[1]);       \
        BSTEP(P##v12[0], P##v12[1], P##v12[2], P##v12[3], P##q3[0]);       \
        BSTEP(P##v11[0], P##v11[1], P##v11[2], P##v11[3], P##q2[3]);       \
        BSTEP(P##v10[0], P##v10[1], P##v10[2], P##v10[3], P##q2[2]);       \
        BSTEP(P##v9[0],  P##v9[1],  P##v9[2],  P##v9[3],  P##q2[1]);       \
        BSTEP(P##v8[0],  P##v8[1],  P##v8[2],  P##v8[3],  P##q2[0]);       \
        BSTEP(P##v7[0],  P##v7[1],  P##v7[2],  P##v7[3],  P##q1[3]);       \
        BSTEP(P##v6[0],  P##v6[1],  P##v6[2],  P##v6[3],  P##q1[2]);       \
        BSTEP(P##v5[0],  P##v5[1],  P##v5[2],  P##v5[3],  P##q1[1]);       \
        BSTEP(P##v4[0],  P##v4[1],  P##v4[2],  P##v4[3],  P##q1[0]);       \
        BSTEP(P##v3[0],  P##v3[1],  P##v3[2],  P##v3[3],  P##q0[3]);       \
        BSTEP(P##v2[0],  P##v2[1],  P##v2[2],  P##v2[3],  P##q0[2]);       \
        BSTEP(P##v1[0],  P##v1[1],  P##v1[2],  P##v1[3],  P##q0[1]);       \
        BSTEP(P##v0[0],  P##v0[1],  P##v0[2],  P##v0[3],  P##q0[0]);       \
    } while (0)
        LOADB(X, 1984);
        for (int k = 0; k + 1 < 61; k += 2) {
            LOADB(Y, 1984 - 16 * (k + 1)); VMWAIT(20); RUNBK(X);
            LOADB(X, 1984 - 16 * (k + 2)); VMWAIT(20); RUNBK(Y);
        }
        LOADB(Y, 1008); VMWAIT(20); RUNBK(X);  // chunk 60 (rows 1024..1039)
        VMWAIT(0); RUNBK(Y);                   // chunk 61 (rows 1008..1023)
#undef RUNBK
#undef BSTEP
        sb[0][lane] = bA0; sb[1][lane] = bA1;
        sb[2][lane] = bO0; sb[3][lane] = bO1;
    }
#undef LOADB

    __syncthreads();

    if (wave == 0) {
        // combine: LSE over all states of alpha_1007 + beta_1007
        const float bA0g = sb[0][lane], bA1g = sb[1][lane];
        const float bO0g = sb[2][lane], bO1g = sb[3][lane];
        // lane masks kill garbage (incl. possible NaN) in lanes >= 50
        const float T0 = (lane <= 50) ? A0 + bA0g : NEG_INF_F;
        const float T1 = (lane < 50)  ? A1 + bA1g : NEG_INF_F;
        const float T2 = (lane < 50)  ? O0 + bO0g : NEG_INF_F;
        const float T3 = (lane < 50)  ? O1 + bO1g : NEG_INF_F;
        float M = fmaxf(fmaxf(T0, T1), fmaxf(T2, T3));
        float S = EXP2(T0 - M) + EXP2(T1 - M) + EXP2(T2 - M) + EXP2(T3 - M);
        #pragma unroll
        for (int off = 32; off >= 1; off >>= 1) {
            const float Mo = __shfl_xor(M, off, 64);
            const float So = __shfl_xor(S, off, 64);
            const float Mn = fmaxf(M, Mo);
            S = S * EXP2(M - Mn) + So * EXP2(Mo - Mn);
            M = Mn;
        }
        if (lane == 0) {
            const float LN2 = 0.6931471805599453f;
            atomicAdd(out, -(M + LOG2(S)) * LN2
                               / ((float)T_LEN * (float)BATCH));
        }
    }
}

// ---------------------------------------------------------------- launch
extern "C" void kernel_launch(void* const* d_in, const int* in_sizes, int n_in,
                              void* d_out, int out_size, void* d_ws, size_t ws_size,
                              hipStream_t stream)
{
    const float* inputs  = (const float*)d_in[0];   // (2000,32,128) f32
    const int*   targets = (const int*)d_in[1];     // (32,100) i32
    float*       out     = (float*)d_out;           // scalar f32

    float4* tabA = (float4*)d_ws;                                   // 51.2 MB
    float*  tabB = (float*)((char*)d_ws + (size_t)BATCH * T_LEN * 50 * 16);

    // wt = WLAST + (W0-WLAST)*exp(-NSTEP*ln2/THALF)
    const float wt = (float)(0.1 + 0.9 * exp(-log(2.0) / 10000.0));

    // out zeroed inside stc_emit (idle lane) — no memset dispatch.
    stc_emit<<<dim3(T_LEN / EROWS, BATCH), dim3(64), 0, stream>>>(
        inputs, targets, tabA, tabB, out, wt);
    stc_scan<<<dim3(BATCH), dim3(128), 0, stream>>>(tabA, tabB, targets, out);
}